// Round 19
// baseline (332.490 us; speedup 1.0000x reference)
//
#include <hip/hip_runtime.h>

typedef unsigned short u16;
typedef unsigned int u32;
typedef __attribute__((ext_vector_type(8))) short bf16x8;
typedef __attribute__((ext_vector_type(8))) u16 u16x8;
typedef __attribute__((ext_vector_type(4))) float f32x4;

#define L2E 1.4426950408889634f

__device__ __forceinline__ u16 f2bf(float f) {
  u32 u = __builtin_bit_cast(u32, f);
  u32 r = (u + 0x7fffu + ((u >> 16) & 1u)) >> 16;
  return (u16)r;
}
__device__ __forceinline__ float bf2f(u16 h) {
  u32 u = ((u32)h) << 16;
  return __builtin_bit_cast(float, u);
}

__device__ __forceinline__ void gload16(const u16* g, u16* l) {
  __builtin_amdgcn_global_load_lds(
      (const __attribute__((address_space(1))) void*)g,
      (__attribute__((address_space(3))) void*)l, 16, 0, 0);
}

__device__ __forceinline__ void stage_half(const u16* gsrc, u16* ldst,
                                           long ld64) {
  gload16(gsrc, ldst);
  gload16(gsrc + ld64, ldst + 4096);
}

__device__ __forceinline__ void dsa(bf16x8 (&af)[2][2], const u16* base,
                                    u32 off0, u32 off1) {
  af[0][0] = *(const bf16x8*)(base + off0);
  af[0][1] = *(const bf16x8*)(base + off1);
  af[1][0] = *(const bf16x8*)(base + 1024 + off0);
  af[1][1] = *(const bf16x8*)(base + 1024 + off1);
}

template <int NF>
__device__ __forceinline__ void dsb(bf16x8 (&bfr)[4][2], const u16* base,
                                    u32 off0, u32 off1) {
#pragma unroll
  for (int fc = 0; fc < NF; ++fc) {
    bfr[fc][0] = *(const bf16x8*)(base + fc * 1024 + off0);
    bfr[fc][1] = *(const bf16x8*)(base + fc * 1024 + off1);
  }
}

template <int Q, int NF>
__device__ __forceinline__ void mfma_quad(f32x4 (&acc)[8][4],
                                          const bf16x8 (&af)[2][2],
                                          const bf16x8 (&bfr)[4][2]) {
#pragma unroll
  for (int fc = 0; fc < NF; ++fc) {
    acc[2 * Q][fc] = __builtin_amdgcn_mfma_f32_16x16x32_bf16(
        af[0][0], bfr[fc][0], acc[2 * Q][fc], 0, 0, 0);
    acc[2 * Q + 1][fc] = __builtin_amdgcn_mfma_f32_16x16x32_bf16(
        af[1][0], bfr[fc][0], acc[2 * Q + 1][fc], 0, 0, 0);
    acc[2 * Q][fc] = __builtin_amdgcn_mfma_f32_16x16x32_bf16(
        af[0][1], bfr[fc][1], acc[2 * Q][fc], 0, 0, 0);
    acc[2 * Q + 1][fc] = __builtin_amdgcn_mfma_f32_16x16x32_bf16(
        af[1][1], bfr[fc][1], acc[2 * Q + 1][fc], 0, 0, 0);
  }
}

// asm s_barrier with memory clobber: compiler memory fence for LDS/DMA ops
// (they cannot cross), register-only MFMA/VALU stay schedulable.
#define BAR asm volatile("s_barrier" ::: "memory")

#define PH_TAIL(Q)                                      \
  do {                                                  \
    __builtin_amdgcn_s_setprio(1);                      \
    mfma_quad<Q, N64>(acc, af, bfr);                    \
    __builtin_amdgcn_s_setprio(0);                      \
  } while (0)

#define WAIT_N64                                        \
  do {                                                  \
    if (N64 == 4)                                       \
      asm volatile("s_waitcnt vmcnt(4)" ::: "memory");  \
    else                                                \
      asm volatile("s_waitcnt vmcnt(3)" ::: "memory");  \
  } while (0)

#define STG_A(tile, half)                                                 \
  if ((tile) < NT)                                                        \
  stage_half(gA + (long)(half) * 128 * lda + (long)(tile) * 64,           \
             As + (((tile)&1) * 2 + (half)) * 8192 + wofs, lda64)

#define STG_B_C(tile, c)                                                  \
  if ((tile) < NT)                                                        \
  gload16(gB + (long)(c) * 64 * ldb + (long)(tile) * 64,                  \
          Bs + (((tile)&1) * N64 + (c)) * 4096 + wofs)

// ---------------------------------------------------------------------------
// PV GEMM: 256 x (64*N64) tile, BK=64, 8 waves, 4-barrier-per-K-tile counted
// vmcnt schedule (R14/R17 validated).  C = A*Bt^T, f32 out scaled by 1/L.
// 1/L computed in the prologue from psum[z][4096][32] (fused stats).
// ---------------------------------------------------------------------------
template <int EPI, int N64>
__global__ __launch_bounds__(512, 2) void gemm256(
    const u16* __restrict__ A, long lda, long sA, const u16* __restrict__ Bt,
    long ldb, long sB, void* __restrict__ Cout, long ldc, long sC, int NT,
    float* __restrict__ psum) {
  __shared__ u16 As[32768];
  __shared__ u16 Bs[N64 * 8192];
  __shared__ float invls[256];

  const int z = blockIdx.z;
  A += (long)z * sA;
  Bt += (long)z * sB;

  const int m0 = blockIdx.x * 256;
  const int n0 = blockIdx.y * (64 * N64);

  const int tid = threadIdx.x;
  const int w = tid >> 6, lane = tid & 63;
  const int wm = w >> 2, wn = w & 3;
  const int g = lane >> 4, l15 = lane & 15, l7 = lane & 7;

  const u32 off0 = (u32)(((0 + g) ^ l7) * 8);
  const u32 off1 = (u32)(((4 + g) ^ l7) * 8);
  const u16* pA = As + wm * 8192 + l15 * 64;
  const u16* pB = Bs + wn * (1024 * N64) + l15 * 64;

  const int trow = tid >> 3;
  const int perm = (tid & 7) ^ ((tid >> 3) & 7);
  const u16* gA = A + (long)(m0 + trow) * lda + perm * 8;
  const u16* gB = Bt + (long)(n0 + trow) * ldb + perm * 8;
  const long lda64 = lda * 64;
  const u32 wofs = w * 512;

  f32x4 acc[8][4];
#pragma unroll
  for (int i = 0; i < 8; ++i)
#pragma unroll
    for (int j = 0; j < N64; ++j) acc[i][j] = (f32x4){0.f, 0.f, 0.f, 0.f};

  stage_half(gA, As + 0 * 8192 + wofs, lda64);
  stage_half(gA + 128 * lda, As + 1 * 8192 + wofs, lda64);
#pragma unroll
  for (int c = 0; c < N64; ++c) STG_B_C(0, c);
#pragma unroll
  for (int c = 0; c < N64; ++c) STG_B_C(1, c);
  if (EPI == 0 && tid < 256) {
    // fused stats: 1/L for this block's rows (synced by the BAR below)
    const float* ps = psum + (long)z * 131072 + (long)(m0 + tid) * 32;
    float l = 0.f;
#pragma unroll
    for (int i = 0; i < 32; ++i) l += ps[i];
    invls[tid] = 1.f / l;
  }
  WAIT_N64;
  BAR;

  bf16x8 af[2][2], bfr[4][2];
  const int niter = NT >> 1;
  for (int it = 0; it < niter; ++it) {
    const int t0 = it * 2;
    dsb<N64>(bfr, pB, off0, off1);  // ph1
    dsa(af, pA, off0, off1);
    BAR;
    PH_TAIL(0);
    dsa(af, pA + 2048, off0, off1);  // ph2
    STG_A(t0 + 1, 0);
    STG_A(t0 + 1, 1);
    BAR;
    PH_TAIL(1);
    dsa(af, pA + 4096, off0, off1);  // ph3
    STG_B_C(t0 + 2, 0);
    STG_B_C(t0 + 2, 1);
    BAR;
    PH_TAIL(2);
    dsa(af, pA + 6144, off0, off1);  // ph4
    STG_B_C(t0 + 2, 2);
    if (N64 == 4) STG_B_C(t0 + 2, 3);
    if (it + 1 == niter) {
      asm volatile("s_waitcnt vmcnt(0)" ::: "memory");
    } else {
      WAIT_N64;
    }
    BAR;
    PH_TAIL(3);
    dsb<N64>(bfr, pB + N64 * 4096, off0, off1);  // ph5
    dsa(af, pA + 16384, off0, off1);
    BAR;
    PH_TAIL(0);
    dsa(af, pA + 16384 + 2048, off0, off1);  // ph6
    STG_A(t0 + 2, 0);
    STG_A(t0 + 2, 1);
    BAR;
    PH_TAIL(1);
    dsa(af, pA + 16384 + 4096, off0, off1);  // ph7
    STG_B_C(t0 + 3, 0);
    STG_B_C(t0 + 3, 1);
    BAR;
    PH_TAIL(2);
    dsa(af, pA + 16384 + 6144, off0, off1);  // ph8
    STG_B_C(t0 + 3, 2);
    if (N64 == 4) STG_B_C(t0 + 3, 3);
    WAIT_N64;
    BAR;
    PH_TAIL(3);
  }

  const int erow0 = m0 + wm * 128 + g * 4;
  const int lrow0 = wm * 128 + g * 4;
  const int ecol0 = n0 + wn * (16 * N64) + l15;
#pragma unroll
  for (int fr = 0; fr < 8; ++fr) {
#pragma unroll
    for (int r = 0; r < 4; ++r) {
#pragma unroll
      for (int fc = 0; fc < N64; ++fc) {
        const int col = ecol0 + fc * 16;
        const long row = erow0 + fr * 16 + r;
        const float inv = invls[lrow0 + fr * 16 + r];
        ((float*)Cout)[(long)z * sC + row * ldc + col] = acc[fr][fc][r] * inv;
      }
    }
  }
}

// ---------------------------------------------------------------------------
// 128x128 GEMM, BK=64 (12 K-iters), slot^=(row&7) swizzle both-sides,
// 4 waves / 32KB LDS -> ~5 blocks/CU (cross-block TLP hides sync stalls;
// measured 830 TF on the projection this session).
// EPI 0 (proj):   C = A*Wcat^T + bias; cols<1536 -> QK, else VT[b][d][s].
// EPI 1 (scores): C = bf16 exp2(s*L2E) at z*sC + row*ldc + col; per-block
//   row sums (128 cols) -> psum[z][4096][32] at n-block index blockIdx.y.
// ---------------------------------------------------------------------------
template <int EPI>
__global__ __launch_bounds__(256) void gemm128(
    const u16* __restrict__ A, long lda, long sA, const u16* __restrict__ Bt,
    long ldb, long sB, u16* __restrict__ Cout, long ldc, long sC,
    const float* __restrict__ bias, u16* __restrict__ VT,
    float* __restrict__ psum, int NT) {
  __shared__ u16 As[128 * 64];  // 16 KB
  __shared__ u16 Bs[128 * 64];

  const int z = blockIdx.z;
  A += (long)z * sA;
  Bt += (long)z * sB;

  const int m0 = blockIdx.x * 128;
  const int n0 = blockIdx.y * 128;

  const int tid = threadIdx.x;
  const int lane = tid & 63;
  const int w = tid >> 6;
  const int wr = w >> 1;
  const int wc = w & 1;

  // staging source (c-invariant perm)
  const int srow = tid >> 3;  // 0..31
  const int scol = ((tid & 7) ^ ((tid >> 3) & 7)) * 8;
  const u16* gA0 = A + (long)(m0 + srow) * lda + scol;
  const u16* gB0 = Bt + (long)(n0 + srow) * ldb + scol;
  u16* lA = As + w * 512;
  u16* lB = Bs + w * 512;

  const int l15 = lane & 15, g = lane >> 4, l7 = lane & 7;
  u32 offA[4][2], offB[4][2];
#pragma unroll
  for (int m = 0; m < 4; ++m)
#pragma unroll
    for (int ks = 0; ks < 2; ++ks) {
      const u32 perm = (u32)(((ks * 4 + g) ^ l7) * 8);
      offA[m][ks] = (u32)((wr * 64 + 16 * m + l15) * 64) + perm;
      offB[m][ks] = (u32)((wc * 64 + 16 * m + l15) * 64) + perm;
    }

  f32x4 acc[4][4];
#pragma unroll
  for (int i = 0; i < 4; ++i)
#pragma unroll
    for (int j = 0; j < 4; ++j) acc[i][j] = (f32x4){0.f, 0.f, 0.f, 0.f};

  for (int kt = 0; kt < NT; ++kt) {
    const int ko = kt * 64;
    __syncthreads();
#pragma unroll
    for (int c = 0; c < 4; ++c) {
      gload16(gA0 + (long)c * 32 * lda + ko, lA + c * 2048);
      gload16(gB0 + (long)c * 32 * ldb + ko, lB + c * 2048);
    }
    __syncthreads();
    bf16x8 af[4][2], bf[4][2];
#pragma unroll
    for (int m = 0; m < 4; ++m) {
      af[m][0] = *(const bf16x8*)(As + offA[m][0]);
      af[m][1] = *(const bf16x8*)(As + offA[m][1]);
    }
#pragma unroll
    for (int n = 0; n < 4; ++n) {
      bf[n][0] = *(const bf16x8*)(Bs + offB[n][0]);
      bf[n][1] = *(const bf16x8*)(Bs + offB[n][1]);
    }
#pragma unroll
    for (int m = 0; m < 4; ++m)
#pragma unroll
      for (int n = 0; n < 4; ++n) {
        acc[m][n] = __builtin_amdgcn_mfma_f32_16x16x32_bf16(af[m][0], bf[n][0],
                                                            acc[m][n], 0, 0, 0);
        acc[m][n] = __builtin_amdgcn_mfma_f32_16x16x32_bf16(af[m][1], bf[n][1],
                                                            acc[m][n], 0, 0, 0);
      }
  }

  const int lrow0 = wr * 64 + (lane >> 4) * 4;  // local row base
  const int ccol0 = n0 + wc * 64 + (lane & 15);

  if (EPI == 0) {
#pragma unroll
    for (int m = 0; m < 4; ++m) {
#pragma unroll
      for (int n = 0; n < 4; ++n) {
        const int col = ccol0 + n * 16;
        const float badd = bias[col];
#pragma unroll
        for (int r = 0; r < 4; ++r) {
          const long row = m0 + lrow0 + m * 16 + r;
          const float v = acc[m][n][r] + badd;
          if (col < 1536) {
            Cout[row * ldc + col] = f2bf(v);
          } else {
            const long b = row >> 12, s = row & 4095;
            VT[(b * 768 + (col - 1536)) * 4096 + s] = f2bf(v);
          }
        }
      }
    }
  } else {
    // scores: store bf16 exp2(s*L2E); per-lane row sums over this wave's
    // 64 cols, 16-lane butterfly (g preserved), cross-wc via LDS.
    float rsum[4][4];
#pragma unroll
    for (int m = 0; m < 4; ++m) {
#pragma unroll
      for (int r = 0; r < 4; ++r) {
        float s_ = 0.f;
#pragma unroll
        for (int n = 0; n < 4; ++n) {
          const int col = ccol0 + n * 16;
          const long row = m0 + lrow0 + m * 16 + r;
          const float e = exp2f(acc[m][n][r] * L2E);
          s_ += e;
          Cout[(long)z * sC + row * ldc + col] = f2bf(e);
        }
        rsum[m][r] = s_;
      }
    }
    float* Ls = (float*)As;  // 128 rows x 2 wc = 1 KB
#pragma unroll
    for (int m = 0; m < 4; ++m)
#pragma unroll
      for (int r = 0; r < 4; ++r) {
        float s_ = rsum[m][r];
#pragma unroll
        for (int o = 1; o < 16; o <<= 1) s_ += __shfl_xor(s_, o, 64);
        rsum[m][r] = s_;
      }
    __syncthreads();  // all LDS reads of the loop retired
    if (l15 == 0) {
#pragma unroll
      for (int m = 0; m < 4; ++m)
#pragma unroll
        for (int r = 0; r < 4; ++r)
          Ls[(lrow0 + m * 16 + r) * 2 + wc] = rsum[m][r];
    }
    __syncthreads();
    if (tid < 128) {
      psum[(long)z * 131072 + (long)(m0 + tid) * 32 + blockIdx.y] =
          Ls[tid * 2] + Ls[tid * 2 + 1];
    }
  }
}

// ---------------------------------------------------------------------------
__global__ __launch_bounds__(256) void f32_to_bf16_kernel(
    const float* __restrict__ in, u16* __restrict__ out, long n) {
  long i0 = (long)blockIdx.x * 256 + threadIdx.x;
  long stride = (long)gridDim.x * 256;
  long n4 = n >> 2;
  for (long i = i0; i < n4; i += stride) {
    float4 f = ((const float4*)in)[i];
    ushort4 o = make_ushort4(f2bf(f.x), f2bf(f.y), f2bf(f.z), f2bf(f.w));
    ((ushort4*)out)[i] = o;
  }
}

// Wcat_t[2304][768] = concat(Wq^T * qs, Wk^T, Wv^T) bf16; kt==0 blocks also
// write the fused bias vector bc.
__global__ __launch_bounds__(256) void wcat_kernel(
    const float* __restrict__ Wq, const float* __restrict__ Wk,
    const float* __restrict__ Wv, u16* __restrict__ Wt, float qs,
    const float* __restrict__ bq, const float* __restrict__ bk,
    const float* __restrict__ bv, float* __restrict__ bc) {
  __shared__ float t[64][65];
  const int kt = blockIdx.x;
  const int nt = blockIdx.y;
  const int sel = nt / 12;
  const float* W = sel == 0 ? Wq : (sel == 1 ? Wk : Wv);
  const float scale = sel == 0 ? qs : 1.f;
  const int n0 = (nt % 12) * 64, k0 = kt * 64;
  if (kt == 0 && threadIdx.x < 64) {
    const float* b = sel == 0 ? bq : (sel == 1 ? bk : bv);
    bc[nt * 64 + threadIdx.x] = b[n0 + threadIdx.x] * scale;
  }
#pragma unroll
  for (int i = 0; i < 16; ++i) {
    int idx = i * 256 + threadIdx.x;
    int r = idx >> 6, c = idx & 63;
    t[r][c] = W[(long)(k0 + r) * 768 + (n0 + c)];
  }
  __syncthreads();
#pragma unroll
  for (int i = 0; i < 16; ++i) {
    int idx = i * 256 + threadIdx.x;
    int ro = idx >> 6, co = idx & 63;
    Wt[(long)(nt * 64 + ro) * 768 + (k0 + co)] = f2bf(t[co][ro] * scale);
  }
}

// ---------------------------------------------------------------------------
extern "C" void kernel_launch(void* const* d_in, const int* in_sizes, int n_in,
                              void* d_out, int out_size, void* d_ws,
                              size_t ws_size, hipStream_t stream) {
  const float* x = (const float*)d_in[0];
  const float* Wq = (const float*)d_in[1];
  const float* bq = (const float*)d_in[2];
  const float* Wk = (const float*)d_in[3];
  const float* bk = (const float*)d_in[4];
  const float* Wv = (const float*)d_in[5];
  const float* bv = (const float*)d_in[6];
  float* out = (float*)d_out;

  const float qs = 0.036084391824351615f;  // 1/sqrt(768)

  // workspace carve
  char* p = (char*)d_ws;
  u16* Wcat = (u16*)p;    p += (size_t)2304 * 768 * 2;
  float* bc = (float*)p;   p += (size_t)2304 * 4;
  u16* xbf = (u16*)p;     p += (size_t)16384 * 768 * 2;
  u16* QK = (u16*)p;      p += (size_t)16384 * 1536 * 2;
  u16* VT = (u16*)p;      p += (size_t)4 * 768 * 4096 * 2;
  float* psumB = (float*)p; p += (size_t)4 * 4096 * 32 * 4;  // 2 MB
  u16* Sbuf = (u16*)p;
  const size_t base = (size_t)(p - (char*)d_ws);
  const size_t sOne = (size_t)4096 * 4096 * 2;
  int grp = 1;
  if (ws_size >= base + 4 * sOne) grp = 4;
  else if (ws_size >= base + 2 * sOne) grp = 2;

  f32_to_bf16_kernel<<<2048, 256, 0, stream>>>(x, xbf, (long)16384 * 768);
  wcat_kernel<<<dim3(12, 36), 256, 0, stream>>>(Wq, Wk, Wv, Wcat, qs, bq, bk,
                                                bv, bc);

  // QKV projection (EPI 0): A=xbf 16384x768, Bt=Wcat 2304x768
  gemm128<0><<<dim3(128, 18, 1), 256, 0, stream>>>(
      xbf, 768, 0, Wcat, 768, 0, QK, 1536, 0, bc, VT, nullptr, 12);

  for (int b0 = 0; b0 < 4; b0 += grp) {
    // scores (EPI 1) on the 830-TF 128^2 structure: 128^2 tiles, grid
    // (32,32,grp) -> ~5 blocks/CU, per-XCD panel set 2.3 MB (L2-resident).
    gemm128<1><<<dim3(32, 32, grp), 256, 0, stream>>>(
        QK + (long)b0 * 4096 * 1536, 1536, (long)4096 * 1536,
        QK + 768 + (long)b0 * 4096 * 1536, 1536, (long)4096 * 1536, Sbuf, 4096,
        (long)4096 * 4096, nullptr, nullptr, psumB + (long)b0 * 131072, 12);
    // PV: A = P_unnorm (DMA-staged); 1/L (32 partials) fused in prologue.
    gemm256<0, 3><<<dim3(16, 4, grp), 512, 0, stream>>>(
        Sbuf, 4096, (long)4096 * 4096, VT + (long)b0 * 768 * 4096, 4096,
        (long)768 * 4096, out + (long)b0 * 4096 * 768, 768, (long)4096 * 768,
        64, psumB + (long)b0 * 131072);
  }
}